// Round 4
// baseline (351.650 us; speedup 1.0000x reference)
//
#include <hip/hip_runtime.h>

// TriMul: B=2, S=256, DIM=128, HID=128
// R1-proven arithmetic (absmax 1.17e-2, bit-stable since R4). R10 = R9 with
// stage2+stage3 FUSED into k_fused (Tt round-trip eliminated):
//  - block = (b, i-tile 16, j-tile 16); per h: 16x16x256 GEMM with per-lane
//    DIRECT global fragment loads (row=l16, k=quad*8 within kk*32 window),
//    the exact 8-MFMA k-ascending chain and (R,L) operand order of R9
//    stage2 -> bit-identical T values; f2b'd into a swizzled LDS tile.
//  - then LN over h / gate / @w_out^T wave-private on the tile, with the
//    exact serial-h stats order, lo+hi pairing, elementwise formulas and
//    out-GEMM kk-chain of R9 stage3 -> bit-identical output.
//  - LDS tile [256 rows][136 pitch] with h-granule XOR swizzle
//    (g ^= 2*((row>>4)&7)) keeps all b128 accesses <=8-way conflicted.
//  - XCD-chunk swizzle: orig = (wg%8)*64 + wg/8 -> each XCD owns 4
//    complete (b,i-tile) groups so A-slices stay L2-resident.
// HARD RULE (R2/R3): never touch arithmetic statements, value-producing
// operand order semantics, reduction pairing, or sigmoid form. absmax
// must stay exactly 0.01171875.

#define SS 256
#define DD 128
#define HH 128

typedef __attribute__((ext_vector_type(8))) short bf16x8;
typedef __attribute__((ext_vector_type(4))) short bf16x4;
typedef __attribute__((ext_vector_type(4))) float f32x4;

__device__ __forceinline__ unsigned short f2b(float f) {
  unsigned u = __builtin_bit_cast(unsigned, f);
  u = (u + 0x7FFFu + ((u >> 16) & 1u)) >> 16;
  return (unsigned short)u;
}
__device__ __forceinline__ float b2f(unsigned short h) {
  return __builtin_bit_cast(float, ((unsigned)h) << 16);
}
__device__ __forceinline__ float sigmoidf_(float x) {
  return 1.0f / (1.0f + expf(-x));
}

// ---------------- stage 0: weight fp32 -> bf16 (x4 vectorized) ----------------
__global__ __launch_bounds__(1024) void k_cvt(
    const float* __restrict__ s0, const float* __restrict__ s1,
    const float* __restrict__ s2, const float* __restrict__ s3,
    const float* __restrict__ s4, const float* __restrict__ s5,
    unsigned short* __restrict__ dst)
{
  int m = blockIdx.x >> 2;
  int e4 = (((blockIdx.x & 3) << 10) | threadIdx.x) << 2;
  const float* s = (m == 0) ? s0 : (m == 1) ? s1 : (m == 2) ? s2
                 : (m == 3) ? s3 : (m == 4) ? s4 : s5;
  f32x4 v = *(const f32x4*)(s + e4);
  bf16x4 r;
  #pragma unroll
  for (int i = 0; i < 4; ++i) r[i] = (short)f2b(v[i]);
  *(bf16x4*)(dst + m * 16384 + e4) = r;
}

// ---------------- stage 1: LN + 5 projections + gates (R9-proven) ----------------
__global__ __launch_bounds__(256, 4) void k_stage1(
    const float* __restrict__ x, const float* __restrict__ mask,
    const float* __restrict__ nw, const float* __restrict__ nb,
    const unsigned short* __restrict__ wb,   // [6][128][128] bf16: L,R,LG,RG,OG,O
    unsigned short* __restrict__ Lt, unsigned short* __restrict__ Rt,
    unsigned short* __restrict__ og)
{
  __shared__ unsigned short xnS[64][136];
  __shared__ unsigned short oS[128][72];
  __shared__ float maskS[64];

  const int tid  = threadIdx.x;
  const int wave = tid >> 6, lane = tid & 63;
  const int quad = lane >> 4, l16 = lane & 15;
  const int r0 = blockIdx.x * 64;
  const int bq = r0 >> 16, iq = (r0 >> 8) & 255, j0 = r0 & 255;

  if (tid < 64) maskS[tid] = mask[r0 + tid];

  const float w0 = nw[lane], w1 = nw[lane + 64];
  const float b0 = nb[lane], b1 = nb[lane + 64];
  float v0a[16], v1a[16];
  #pragma unroll
  for (int rr = 0; rr < 16; ++rr) {
    const float* xr = x + (size_t)(r0 + wave * 16 + rr) * DD;
    v0a[rr] = xr[lane];
    v1a[rr] = xr[lane + 64];
  }
  #pragma unroll
  for (int rr = 0; rr < 16; ++rr) {
    int r = wave * 16 + rr;
    float v0 = v0a[rr], v1 = v1a[rr];
    float s = v0 + v1;
    #pragma unroll
    for (int o = 32; o; o >>= 1) s += __shfl_xor(s, o);
    float mu = s * (1.0f / 128.0f);
    float d0 = v0 - mu, d1 = v1 - mu;
    float q = d0 * d0 + d1 * d1;
    #pragma unroll
    for (int o = 32; o; o >>= 1) q += __shfl_xor(q, o);
    float rs = rsqrtf(q * (1.0f / 128.0f) + 1e-5f);
    xnS[r][lane]      = f2b(d0 * rs * w0 + b0);
    xnS[r][lane + 64] = f2b(d1 * rs * w1 + b1);
  }
  __syncthreads();

  const int h0 = wave * 32;
  const int jl = quad * 4;

  auto coopStore = [&](unsigned short* dstBase) {
    int h = tid >> 1, half = tid & 1;
    const bf16x8* s = (const bf16x8*)&oS[h][half * 32];
    bf16x8* d = (bf16x8*)(dstBase +
        ((((size_t)bq * 128 + h) * 256 + iq) * 256 + j0 + half * 32));
    d[0] = s[0]; d[1] = s[1]; d[2] = s[2]; d[3] = s[3];
  };

  auto gatedCompute = [&](const unsigned short* __restrict__ Wv,
                          const unsigned short* __restrict__ Wg,
                          f32x4 (&aV)[4][2], f32x4 (&aG)[4][2]) {
    const unsigned short* pv = Wv + (h0 + l16) * 128 + quad * 8;
    const unsigned short* pg = Wg + (h0 + l16) * 128 + quad * 8;
    #pragma unroll
    for (int rt = 0; rt < 4; ++rt)
      #pragma unroll
      for (int n = 0; n < 2; ++n) {
        aV[rt][n] = f32x4{0.f, 0.f, 0.f, 0.f};
        aG[rt][n] = f32x4{0.f, 0.f, 0.f, 0.f};
      }
    bf16x8 bv[2], bg[2], bvn[2], bgn[2];
    #pragma unroll
    for (int n = 0; n < 2; ++n) {
      bv[n] = *(const bf16x8*)(pv + n * 2048);
      bg[n] = *(const bf16x8*)(pg + n * 2048);
    }
    #pragma unroll
    for (int kk = 0; kk < 4; ++kk) {
      if (kk < 3) {
        #pragma unroll
        for (int n = 0; n < 2; ++n) {
          bvn[n] = *(const bf16x8*)(pv + n * 2048 + (kk + 1) * 32);
          bgn[n] = *(const bf16x8*)(pg + n * 2048 + (kk + 1) * 32);
        }
      }
      #pragma unroll
      for (int rt = 0; rt < 4; ++rt) {
        bf16x8 a = *(const bf16x8*)&xnS[rt * 16 + l16][kk * 32 + quad * 8];
        #pragma unroll
        for (int n = 0; n < 2; ++n) {
          aG[rt][n] = __builtin_amdgcn_mfma_f32_16x16x32_bf16(a, bg[n], aG[rt][n], 0, 0, 0);
          aV[rt][n] = __builtin_amdgcn_mfma_f32_16x16x32_bf16(a, bv[n], aV[rt][n], 0, 0, 0);
        }
      }
      #pragma unroll
      for (int n = 0; n < 2; ++n) { bv[n] = bvn[n]; bg[n] = bgn[n]; }
    }
  };

  auto gatedEpilogue = [&](f32x4 (&aV)[4][2], f32x4 (&aG)[4][2]) {
    #pragma unroll
    for (int rt = 0; rt < 4; ++rt)
      #pragma unroll
      for (int n = 0; n < 2; ++n) {
        bf16x4 p;
        #pragma unroll
        for (int rg = 0; rg < 4; ++rg) {
          float g = sigmoidf_(aG[rt][n][rg]);
          p[rg] = (short)f2b(aV[rt][n][rg] * maskS[rt * 16 + jl + rg] * g);
        }
        *(bf16x4*)&oS[h0 + n * 16 + l16][rt * 16 + jl] = p;
      }
  };

  f32x4 aV[4][2], aG[4][2];

  // ---- LEFT ----
  gatedCompute(wb + 0 * 16384, wb + 2 * 16384, aV, aG);
  gatedEpilogue(aV, aG);
  __syncthreads();
  coopStore(Lt);
  // ---- RIGHT compute overlapped with Lt store ----
  gatedCompute(wb + 1 * 16384, wb + 3 * 16384, aV, aG);
  __syncthreads();
  gatedEpilogue(aV, aG);
  __syncthreads();
  coopStore(Rt);

  // ---- OUT GATE (operand-swapped epilogue, R9-proven) ----
  {
    const unsigned short* po = wb + 4 * 16384 + (h0 + l16) * 128 + quad * 8;
    f32x4 aO[4][2];
    #pragma unroll
    for (int rt = 0; rt < 4; ++rt)
      #pragma unroll
      for (int n = 0; n < 2; ++n) aO[rt][n] = f32x4{0.f, 0.f, 0.f, 0.f};
    bf16x8 bo[2], bon[2];
    #pragma unroll
    for (int n = 0; n < 2; ++n) bo[n] = *(const bf16x8*)(po + n * 2048);
    #pragma unroll
    for (int kk = 0; kk < 4; ++kk) {
      if (kk < 3) {
        #pragma unroll
        for (int n = 0; n < 2; ++n)
          bon[n] = *(const bf16x8*)(po + n * 2048 + (kk + 1) * 32);
      }
      #pragma unroll
      for (int rt = 0; rt < 4; ++rt) {
        bf16x8 a = *(const bf16x8*)&xnS[rt * 16 + l16][kk * 32 + quad * 8];
        #pragma unroll
        for (int n = 0; n < 2; ++n)
          aO[rt][n] = __builtin_amdgcn_mfma_f32_16x16x32_bf16(bo[n], a, aO[rt][n], 0, 0, 0);
      }
      #pragma unroll
      for (int n = 0; n < 2; ++n) bo[n] = bon[n];
    }
    __syncthreads();
    unsigned short* ogS = &oS[0][0];
    #pragma unroll
    for (int rt = 0; rt < 4; ++rt)
      #pragma unroll
      for (int n = 0; n < 2; ++n) {
        bf16x4 p;
        #pragma unroll
        for (int rg = 0; rg < 4; ++rg)
          p[rg] = (short)f2b(sigmoidf_(aO[rt][n][rg]));
        *(bf16x4*)&ogS[(rt * 16 + l16) * 136 + h0 + n * 16 + quad * 4] = p;
      }
  }
  __syncthreads();
  {
    int j = tid >> 2, qq = tid & 3;
    const unsigned short* ogS = &oS[0][0];
    const bf16x8* sp = (const bf16x8*)&ogS[j * 136 + qq * 32];
    bf16x8* d = (bf16x8*)(og + (size_t)(r0 + j) * HH + qq * 32);
    d[0] = sp[0]; d[1] = sp[1]; d[2] = sp[2]; d[3] = sp[3];
  }
}

// ---------------- fused stage 2+3 ----------------
// block = (b, i-tile 16, j-tile 16). Phase A: per-h 16x16x256 GEMM with
// direct per-lane global fragment loads, bit-identical 8-MFMA chain.
// Phase B: LN over h / gate / @w_out^T, wave-private on LDS tile.
__global__ __launch_bounds__(256, 2) void k_fused(
    const unsigned short* __restrict__ Lt, const unsigned short* __restrict__ Rt,
    const unsigned short* __restrict__ og,
    const float* __restrict__ onw, const float* __restrict__ onb,
    const unsigned short* __restrict__ wbO, float* __restrict__ out)
{
  // tile [row = iL*16+jL][h], pitch 136 u16; h-granule (8B=4 h) XOR-swizzled
  // by 2*((row>>4)&7) -> all b128 accesses stay contiguous & <=8-way banked.
  __shared__ unsigned short vvF[256 * 136];
  __shared__ float onwS[128], onbS[128];

  const int tid  = threadIdx.x;
  const int wave = tid >> 6, lane = tid & 63;
  const int quad = lane >> 4, l16 = lane & 15;

  // XCD-chunk swizzle: heuristic xcd = wg%8; orig = (wg%8)*64 + wg/8 gives
  // each XCD 64 consecutive orig ids = 4 complete (b,i-tile) groups.
  const int wg   = blockIdx.x;
  const int orig = (wg & 7) * 64 + (wg >> 3);
  const int b  = orig >> 8;
  const int i0 = ((orig >> 4) & 15) * 16;
  const int j0 = (orig & 15) * 16;

  if (tid < 128) { onwS[tid] = onw[tid]; onbS[tid] = onb[tid]; }

  // ---- phase A ----
  // fragment rows: L row = i0+l16 (second operand), R row = j0+l16 (first);
  // k-offset = kk*32 + quad*8. acc chain = mfma(Rf, Lf) kk 0..7 ascending —
  // exactly R9 stage2's products, order, and operand roles.
  const unsigned short* Lp = Lt + ((size_t)(b * 128 + wave * 32) * 256 + (i0 + l16)) * 256 + quad * 8;
  const unsigned short* Rp = Rt + ((size_t)(b * 128 + wave * 32) * 256 + (j0 + l16)) * 256 + quad * 8;

  #pragma unroll 1
  for (int g8 = 0; g8 < 4; ++g8) {
    bf16x8 pk[4];
    #pragma unroll
    for (int hg = 0; hg < 8; ++hg) {
      bf16x8 lf[8], rf[8];
      #pragma unroll
      for (int kk = 0; kk < 8; ++kk) {
        rf[kk] = *(const bf16x8*)(Rp + kk * 32);
        lf[kk] = *(const bf16x8*)(Lp + kk * 32);
      }
      f32x4 acc = f32x4{0.f, 0.f, 0.f, 0.f};
      #pragma unroll
      for (int kk = 0; kk < 8; ++kk)
        acc = __builtin_amdgcn_mfma_f32_16x16x32_bf16(rf[kk], lf[kk], acc, 0, 0, 0);
      #pragma unroll
      for (int rg = 0; rg < 4; ++rg) pk[rg][hg] = (short)f2b(acc[rg]);
      Lp += 65536; Rp += 65536;
    }
    const int h0 = wave * 32 + g8 * 8;        // 8-h group, b128-aligned
    #pragma unroll
    for (int rg = 0; rg < 4; ++rg) {
      int row = l16 * 16 + quad * 4 + rg;     // i=l16 (2nd op), j=quad*4+rg (1st)
      *(bf16x8*)&vvF[row * 136 + ((((h0 >> 2) ^ ((row >> 3) & 14)) << 2))] = pk[rg];
    }
  }
  __syncthreads();   // sole block-wide barrier

  // ---- phase B (wave-private rows [64*wave, 64*wave+64)) ----
  const int iL = tid >> 4, jL = tid & 15;
  const unsigned short* ogp = og +
      ((size_t)b * 65536 + (size_t)(i0 + iL) * 256 + (j0 + jL)) * 128;
  bf16x8 gpre[16];
  #pragma unroll
  for (int c = 0; c < 16; ++c) gpre[c] = *(const bf16x8*)(ogp + c * 8);

  // stats: identical serial h-order (lo 0..63, hi 64..127) and lo+hi pairing
  float mu, rs;
  {
    float sl = 0.f, ql = 0.f, sh = 0.f, qh = 0.f;
    #pragma unroll
    for (int c = 0; c < 8; ++c) {
      bf16x8 v8 = *(const bf16x8*)&vvF[tid * 136 + (((c * 2) ^ ((tid >> 3) & 14)) << 2)];
      #pragma unroll
      for (int e = 0; e < 8; ++e) { float v = b2f((unsigned short)v8[e]); sl += v; ql += v * v; }
    }
    #pragma unroll
    for (int c = 8; c < 16; ++c) {
      bf16x8 v8 = *(const bf16x8*)&vvF[tid * 136 + (((c * 2) ^ ((tid >> 3) & 14)) << 2)];
      #pragma unroll
      for (int e = 0; e < 8; ++e) { float v = b2f((unsigned short)v8[e]); sh += v; qh += v * v; }
    }
    float s = sl + sh, q = ql + qh;
    mu = s * (1.0f / 128.0f);
    float var = q * (1.0f / 128.0f) - mu * mu;
    rs = rsqrtf(var + 1e-5f);
  }

  // elementwise normalize * gate (same formulas), write back to tile
  #pragma unroll
  for (int c = 0; c < 16; ++c) {
    unsigned short* vp = &vvF[tid * 136 + (((c * 2) ^ ((tid >> 3) & 14)) << 2)];
    bf16x8 tv = *(bf16x8*)vp;
    bf16x8 gv = gpre[c];
    bf16x8 r;
    #pragma unroll
    for (int e = 0; e < 8; ++e) {
      int hh = c * 8 + e;
      float v = (b2f((unsigned short)tv[e]) - mu) * rs * onwS[hh] + onbS[hh];
      r[e] = (short)f2b(v * b2f((unsigned short)gv[e]));
    }
    *(bf16x8*)vp = r;
  }
  asm volatile("s_waitcnt lgkmcnt(0)" ::: "memory");

  // out[j][d] GEMM: operand-swapped (w_out first) exactly as R9 stage3;
  // wave handles i-rows [wave*4, wave*4+4), each = 16 j-rows (its own lanes).
  #pragma unroll
  for (int ii = 0; ii < 4; ++ii) {
    const int iO = wave * 4 + ii;
    f32x4 acc[8];
    #pragma unroll
    for (int nt = 0; nt < 8; ++nt) acc[nt] = f32x4{0.f, 0.f, 0.f, 0.f};
    #pragma unroll
    for (int kk = 0; kk < 4; ++kk) {
      int row = iO * 16 + l16;
      bf16x8 xv = *(const bf16x8*)&vvF[row * 136 +
          ((((kk * 32 + quad * 8) >> 2) ^ ((row >> 3) & 14)) << 2)];
      #pragma unroll
      for (int nt = 0; nt < 8; ++nt) {
        bf16x8 wv = *(const bf16x8*)(wbO + (nt * 16 + l16) * 128 + kk * 32 + quad * 8);
        acc[nt] = __builtin_amdgcn_mfma_f32_16x16x32_bf16(wv, xv, acc[nt], 0, 0, 0);
      }
    }
    float* op = out + ((size_t)(b * 256 + i0 + iO) * 256 + j0 + l16) * 128 + quad * 4;
    #pragma unroll
    for (int nt = 0; nt < 8; ++nt)
      *(f32x4*)(op + nt * 16) = acc[nt];
  }
}

extern "C" void kernel_launch(void* const* d_in, const int* in_sizes, int n_in,
                              void* d_out, int out_size, void* d_ws, size_t ws_size,
                              hipStream_t stream)
{
  const float* x    = (const float*)d_in[0];
  const float* mask = (const float*)d_in[1];
  const float* nw   = (const float*)d_in[2];
  const float* nb   = (const float*)d_in[3];
  const float* wL   = (const float*)d_in[4];
  const float* wR   = (const float*)d_in[5];
  const float* wLG  = (const float*)d_in[6];
  const float* wRG  = (const float*)d_in[7];
  const float* wOG  = (const float*)d_in[8];
  const float* onw  = (const float*)d_in[9];
  const float* onb  = (const float*)d_in[10];
  const float* wO   = (const float*)d_in[11];

  char* ws = (char*)d_ws;
  unsigned short* wb = (unsigned short*)ws;
  unsigned short* og = (unsigned short*)(ws + (1 << 18));
  unsigned short* Lt = (unsigned short*)(ws + (1 << 18) + 1 * (size_t)(1 << 25));
  unsigned short* Rt = (unsigned short*)(ws + (1 << 18) + 2 * (size_t)(1 << 25));

  k_cvt<<<24, 1024, 0, stream>>>(wL, wR, wLG, wRG, wOG, wO, wb);
  k_stage1<<<2048, 256, 0, stream>>>(x, mask, nw, nb, wb, Lt, Rt, og);
  k_fused<<<512, 256, 0, stream>>>(Lt, Rt, og, onw, onb, wb + 5 * 16384, (float*)d_out);
}